// Round 5
// baseline (284.111 us; speedup 1.0000x reference)
//
#include <hip/hip_runtime.h>

typedef __bf16 bf16x8 __attribute__((ext_vector_type(8)));
typedef float f32x4 __attribute__((ext_vector_type(4)));
typedef unsigned short u16x8 __attribute__((ext_vector_type(8)));
typedef int i32x4 __attribute__((ext_vector_type(4)));

#define M_TOT 8192
#define K_TOT 4096
#define N_TOT 4096
#define BM 256
#define BN 256
#define BK 64
#define NT (K_TOT / BK)   // 64

__device__ __forceinline__ unsigned short f2bf(float f) {
  union { float f; unsigned int u; } v; v.f = f;
  unsigned int u = v.u;
  return (unsigned short)((u + 0x7FFFu + ((u >> 16) & 1u)) >> 16);  // RNE
}

// weight[o][i] = bf16(codebook[o, indices[o,i]]); one thread = 8 contiguous elems
__global__ __launch_bounds__(256) void deq_w(const float* __restrict__ cb,
                                             const int* __restrict__ idx,
                                             unsigned short* __restrict__ Wb) {
  size_t base = ((size_t)blockIdx.x * 256 + threadIdx.x) * 8;
  const float* crow = cb + ((base >> 12) << 8);  // row = base/4096, 256 floats/row
  i32x4 i0 = *(const i32x4*)(idx + base);
  i32x4 i1 = *(const i32x4*)(idx + base + 4);
  u16x8 o;
#pragma unroll
  for (int j = 0; j < 4; ++j) { o[j] = f2bf(crow[i0[j]]); o[4 + j] = f2bf(crow[i1[j]]); }
  *(u16x8*)(Wb + base) = o;
}

// x f32 -> bf16
__global__ __launch_bounds__(256) void conv_x(const float* __restrict__ X,
                                              unsigned short* __restrict__ Xc) {
  size_t base = ((size_t)blockIdx.x * 256 + threadIdx.x) * 8;
  f32x4 a = *(const f32x4*)(X + base);
  f32x4 b = *(const f32x4*)(X + base + 4);
  u16x8 o;
#pragma unroll
  for (int j = 0; j < 4; ++j) { o[j] = f2bf(a[j]); o[4 + j] = f2bf(b[j]); }
  *(u16x8*)(Xc + base) = o;
}

#define GLDS16(g, l)                                                      \
  __builtin_amdgcn_global_load_lds(                                       \
      (__attribute__((address_space(1))) void*)(g),                       \
      (__attribute__((address_space(3))) void*)(l), 16, 0, 0)

// ============================================================================
// 256x256 tile, BK=64, 8 waves (2M x 4N), double-buffered 128KB LDS.
// (m-half, n-half) quadrant phases with fragment reuse; reads for phase p+1
// issued INSIDE phase p's MFMA cluster (sched_group_barrier-pinned) so the
// LDS read port runs under the matrix pipe. Read pattern per wave per tile:
// p0-head 12 (A-m0 8 + B-n0 4); in-p0 4 (B-n1); in-p1 8 (A-m1); p2,p3: 0.
// Barriers: p1-end (gates B(t+2) staging into current B region: all waves'
// B(t) reads complete by p1's lgkm0), tile-end (after vmcnt(4)).
// Staging per tile t: A(t+1)h0 @p0, A(t+1)h1 @p1 (other buffer); B(t+2)h0
// @p2, B(t+2)h1 @p3 (current buffer's B region). Tile-end vmcnt(4) retires
// B(t+1)+A(t+1) (FIFO: [B(t+1)4, A(t+1)4, B(t+2)4]), leaving B(t+2) in
// flight -- never drains to 0 in the main loop.
// ============================================================================
__global__ __launch_bounds__(512, 2) void gemm8(const unsigned short* __restrict__ A,
                                                const unsigned short* __restrict__ B,
                                                const float* __restrict__ bias,
                                                float* __restrict__ C) {
  __shared__ __attribute__((aligned(128))) char lds[131072];

  const int tid = threadIdx.x;
  const int lane = tid & 63;
  const int wm = (tid >> 6) >> 2;   // 0..1
  const int wn = (tid >> 6) & 3;    // 0..3
  const int lr = lane & 15;

  const int bid = blockIdx.x;                    // nwg = 512 = 8 * 64, bijective
  const int swz = (bid & 7) * 64 + (bid >> 3);
  const int bm = swz >> 4;                       // 0..31
  const int bn = swz & 15;                       // 0..15

  const unsigned short* Ap = A + (size_t)bm * BM * K_TOT;
  const unsigned short* Bp = B + (size_t)bn * BN * K_TOT;

  // staging: 512 thr x 16B = 64 rows/issue, 2 issues per 128-row half
  const int srow = tid >> 3;                              // 0..63
  const int sgcol = (((tid & 7) * 16) ^ ((srow & 7) << 4)) >> 1;  // elem col (inv swizzle)
  const int wavebase = (tid & 448) << 4;                  // wave-uniform LDS base part

  // fragment-read constants (swizzled byte cols for k-halves 0/1)
  const int cs0 = (((lane >> 4) << 4)) ^ ((lr & 7) << 4);
  const int cs1 = (64 + ((lane >> 4) << 4)) ^ ((lr & 7) << 4);
  const int rowA0 = (wm * 128 + lr) * 128;          // byte base of A frags
  const int rowB0 = 32768 + (wn * 64 + lr) * 128;   // byte base of B frags

#define RD(off) (*(const bf16x8*)(lds + (off)))
#define STAGE(GB, TK, RB, LOFF)                                               \
  { _Pragma("unroll")                                                         \
    for (int ii = 0; ii < 2; ++ii) {                                          \
      GLDS16((GB) + (size_t)((RB) + ii * 64 + srow) * K_TOT + (TK) + sgcol,   \
             lds + (LOFF) + ii * 8192 + wavebase);                            \
    } }
#define BARRIER()                       \
  {                                     \
    asm volatile("" ::: "memory");      \
    __builtin_amdgcn_s_barrier();       \
    asm volatile("" ::: "memory");      \
  }
#define LGKM0() asm volatile("s_waitcnt lgkmcnt(0)" ::: "memory")
#define SGB(mask, n) __builtin_amdgcn_sched_group_barrier((mask), (n), 0)

// 4 MFMA for one m-frag MF of quadrant (MH, NH): A regs AV[MF*2+kh], B regs
// BV[nf*2+kh] (nf local 0/1). acc[MH*4+MF][NH*2+nf].
#define QMF(MH, NH, AV, BV, MF)                                                          \
  {                                                                                      \
    acc[(MH)*4+(MF)][(NH)*2+0] = __builtin_amdgcn_mfma_f32_16x16x32_bf16(                \
        AV[(MF)*2+0], BV[0], acc[(MH)*4+(MF)][(NH)*2+0], 0, 0, 0);                       \
    acc[(MH)*4+(MF)][(NH)*2+0] = __builtin_amdgcn_mfma_f32_16x16x32_bf16(                \
        AV[(MF)*2+1], BV[1], acc[(MH)*4+(MF)][(NH)*2+0], 0, 0, 0);                       \
    acc[(MH)*4+(MF)][(NH)*2+1] = __builtin_amdgcn_mfma_f32_16x16x32_bf16(                \
        AV[(MF)*2+0], BV[2], acc[(MH)*4+(MF)][(NH)*2+1], 0, 0, 0);                       \
    acc[(MH)*4+(MF)][(NH)*2+1] = __builtin_amdgcn_mfma_f32_16x16x32_bf16(                \
        AV[(MF)*2+1], BV[3], acc[(MH)*4+(MF)][(NH)*2+1], 0, 0, 0);                       \
  }

#define TILE(T, BO, STG_A, STG_B, VMF)                                            \
  {                                                                               \
    bf16x8 Am[8], Am2[8], Bn[4], Bn2[4];                                          \
    /* ---------- p0: head reads (A m0: 8, B n0: 4); stage A(T+1)h0 ---------- */ \
    _Pragma("unroll") for (int r = 0; r < 4; ++r) {                               \
      Am[r*2+0] = RD((BO) + rowA0 + r * 2048 + cs0);                              \
      Am[r*2+1] = RD((BO) + rowA0 + r * 2048 + cs1);                              \
    }                                                                             \
    _Pragma("unroll") for (int n = 0; n < 2; ++n) {                               \
      Bn[n*2+0] = RD((BO) + rowB0 + n * 2048 + cs0);                              \
      Bn[n*2+1] = RD((BO) + rowB0 + n * 2048 + cs1);                              \
    }                                                                             \
    if (STG_A) STAGE(Ap, ((T) + 1) * BK, 0, ((BO) ^ 65536) + 0);                  \
    LGKM0();                                                                      \
    __builtin_amdgcn_s_setprio(1);                                                \
    QMF(0, 0, Am, Bn, 0);                                                         \
    SGB(0x8, 4);                                                                  \
    _Pragma("unroll") for (int n = 0; n < 2; ++n) {                               \
      Bn2[n*2+0] = RD((BO) + rowB0 + 4096 + n * 2048 + cs0);                      \
      Bn2[n*2+1] = RD((BO) + rowB0 + 4096 + n * 2048 + cs1);                      \
    }                                                                             \
    SGB(0x100, 4);                                                                \
    QMF(0, 0, Am, Bn, 1);                                                         \
    QMF(0, 0, Am, Bn, 2);                                                         \
    QMF(0, 0, Am, Bn, 3);                                                         \
    SGB(0x8, 12);                                                                 \
    __builtin_amdgcn_s_setprio(0);                                                \
    /* ---------- p1: MFMA (m0,n1); pre-read A m1 (8); stage A(T+1)h1 -------- */ \
    if (STG_A) STAGE(Ap, ((T) + 1) * BK, 128, ((BO) ^ 65536) + 16384);            \
    LGKM0();                                                                      \
    __builtin_amdgcn_s_setprio(1);                                                \
    QMF(0, 1, Am, Bn2, 0);                                                        \
    SGB(0x8, 4);                                                                  \
    _Pragma("unroll") for (int r = 0; r < 4; ++r) {                               \
      Am2[r*2+0] = RD((BO) + rowA0 + 8192 + r * 2048 + cs0);                      \
      Am2[r*2+1] = RD((BO) + rowA0 + 8192 + r * 2048 + cs1);                      \
    }                                                                             \
    SGB(0x100, 8);                                                                \
    QMF(0, 1, Am, Bn2, 1);                                                        \
    QMF(0, 1, Am, Bn2, 2);                                                        \
    QMF(0, 1, Am, Bn2, 3);                                                        \
    SGB(0x8, 12);                                                                 \
    __builtin_amdgcn_s_setprio(0);                                                \
    BARRIER();  /* all waves' B(t) reads complete -> B region reusable */         \
    /* ---------- p2: MFMA (m1,n0); stage B(T+2)h0 --------------------------- */ \
    if (STG_B) STAGE(Bp, ((T) + 2) * BK, 0, (BO) + 32768);                        \
    LGKM0();                                                                      \
    __builtin_amdgcn_s_setprio(1);                                                \
    QMF(1, 0, Am2, Bn, 0);                                                        \
    QMF(1, 0, Am2, Bn, 1);                                                        \
    QMF(1, 0, Am2, Bn, 2);                                                        \
    QMF(1, 0, Am2, Bn, 3);                                                        \
    __builtin_amdgcn_s_setprio(0);                                                \
    /* ---------- p3: MFMA (m1,n1); stage B(T+2)h1; boundary ----------------- */ \
    if (STG_B) STAGE(Bp, ((T) + 2) * BK, 128, (BO) + 49152);                      \
    __builtin_amdgcn_s_setprio(1);                                                \
    QMF(1, 1, Am2, Bn2, 0);                                                       \
    QMF(1, 1, Am2, Bn2, 1);                                                       \
    QMF(1, 1, Am2, Bn2, 2);                                                       \
    QMF(1, 1, Am2, Bn2, 3);                                                       \
    __builtin_amdgcn_s_setprio(0);                                                \
    asm volatile("s_waitcnt vmcnt(" VMF ")" ::: "memory");                        \
    BARRIER();                                                                    \
  }

  f32x4 acc[8][4] = {};

  // ---- prologue: stage B(0), A(0), B(1); retire B(0)+A(0); B(1) in flight ----
  STAGE(Bp, 0, 0, 32768);
  STAGE(Bp, 0, 128, 49152);
  STAGE(Ap, 0, 0, 0);
  STAGE(Ap, 0, 128, 16384);
  STAGE(Bp, BK, 0, 65536 + 32768);
  STAGE(Bp, BK, 128, 65536 + 49152);
  asm volatile("s_waitcnt vmcnt(4)" ::: "memory");
  BARRIER();

  // main loop: tiles 0..NT-3 fully pipelined; last two tiles specialized
  for (int t = 0; t < NT - 2; t += 2) {
    TILE(t,     0,     1, 1, "4");
    TILE(t + 1, 65536, 1, 1, "4");
  }
  TILE(NT - 2, 0,     1, 0, "0");
  TILE(NT - 1, 65536, 0, 0, "0");

  // ---- epilogue: C = acc + bias ----
  const int lg4 = (lane >> 4) << 2;
#pragma unroll
  for (int nf = 0; nf < 4; ++nf) {
    const int col = bn * BN + wn * 64 + nf * 16 + lr;
    const float bv = bias[col];
#pragma unroll
    for (int mf = 0; mf < 8; ++mf) {
      const int row0 = bm * BM + wm * 128 + mf * 16 + lg4;
      float* cp = C + (size_t)row0 * N_TOT + col;
#pragma unroll
      for (int j = 0; j < 4; ++j) cp[(size_t)j * N_TOT] = acc[mf][nf][j] + bv;
    }
  }
#undef RD
#undef STAGE
#undef BARRIER
#undef LGKM0
#undef SGB
#undef QMF
#undef TILE
}

extern "C" void kernel_launch(void* const* d_in, const int* in_sizes, int n_in,
                              void* d_out, int out_size, void* d_ws, size_t ws_size,
                              hipStream_t stream) {
  const float* x    = (const float*)d_in[0];   // [4,2048,4096] f32
  const float* cb   = (const float*)d_in[1];   // [4096,256]   f32
  const float* bias = (const float*)d_in[2];   // [4096]       f32
  const int*   idx  = (const int*)d_in[3];     // [4096,4096]  int

  float* out = (float*)d_out;                  // [4,2048,4096] f32

  unsigned short* Wb = (unsigned short*)d_ws;                                      // 32 MB
  unsigned short* Xc = (unsigned short*)((char*)d_ws + (size_t)N_TOT * K_TOT * 2); // 64 MB

  deq_w<<<(N_TOT * (size_t)K_TOT) / (8 * 256), 256, 0, stream>>>(cb, idx, Wb);
  conv_x<<<((size_t)M_TOT * K_TOT) / (8 * 256), 256, 0, stream>>>(x, Xc);
  // (8192/256) * (4096/256) = 32*16 = 512 blocks, 512 threads
  gemm8<<<512, 512, 0, stream>>>(Xc, Wb, bias, out);
}